// Round 16
// baseline (2600.712 us; speedup 1.0000x reference)
//
#include <hip/hip_runtime.h>

// GRU B=64, T=512, IN=128, H=512, L=2, OUT=1 (fp32 in/out).
// R14 (resubmit; Round 15 was a GPUAcquisitionTimeout, kernel never ran):
// serial-first-then-batch retry (fixS), replacing R13b's
// batch-first fixB (2561us regression) and R12's all-serial chain (1702us).
//   R13b post-mortem: its parallel rounds fired 64/320 cyc after the
//   initial probes, but staleness persists ~1200 cyc (store visibility),
//   so both rounds were ALWAYS wasted (extra RTTs + MALL churn: WRITE
//   131->195MB, FETCH +19%), then it ran R12's serial chain anyway.
//   fixS: (1) serial fix4 on the FIRST stale chunk only -- its spin is the
//   proven rate-limiter and absorbs the visibility wait for the batch;
//   (2) ONE parallel re-probe of the rest (producers store ~simultaneously,
//   so they're valid now; 1 RTT replaces 7 serialized RTTs);
//   (3) serialized fix4 fallback for stragglers. Probe rate <= R12.
// History: R9=1723 R10(remap)=2906 R11(reg-direct)=1935 R12(agent-spec)=1702
//          R13b(batch-first)=2561. R7/R8 unbounded fixN = fabric storm.

constexpr int Bb = 64, Tt = 512, DIN = 128, Hh = 512;
constexpr int BH = Bb * Hh;
constexpr int S0 = 644;    // LDS A-row stride (u32), layer0: 128 x + 512 h + 4 pad
constexpr int S1 = 1028;   // layer1: 512 h0 + 512 h1 + 4 pad
constexpr int PR = 20;     // partials row stride: conflict-free (2-way) writes

typedef float  f32x4  __attribute__((ext_vector_type(4)));
typedef short  bf16x8 __attribute__((ext_vector_type(8)));
typedef int    i32x4  __attribute__((ext_vector_type(4)));
typedef unsigned long long u64;

#define MFMA16 __builtin_amdgcn_mfma_f32_16x16x32_bf16

__device__ __forceinline__ unsigned rne_bf16(unsigned xb){
    return (xb + 0x7FFFu + ((xb >> 16) & 1u)) >> 16;
}
__device__ __forceinline__ unsigned pack_split(float x){
    unsigned hb = rne_bf16(__float_as_uint(x));
    float hf = __uint_as_float(hb << 16);
    unsigned lb = rne_bf16(__float_as_uint(x - hf));
    return (hb << 16) | lb;
}
__device__ __forceinline__ float unpack_f32(unsigned u){
    return __uint_as_float(u & 0xFFFF0000u) + __uint_as_float(u << 16);
}

union FragU { unsigned w[4]; bf16x8 v; };

__device__ __forceinline__ void make_wfrag(const float* p, bf16x8& wh, bf16x8& wl){
    FragU hi, lo;
#pragma unroll
    for (int i = 0; i < 4; ++i){
        unsigned pa = pack_split(p[2*i]), pb = pack_split(p[2*i+1]);
        hi.w[i] = (pa >> 16) | (pb & 0xFFFF0000u);
        lo.w[i] = (pa & 0xFFFFu) | (pb << 16);
    }
    wh = hi.v; wl = lo.v;
}
// hi word = [b3,b2,a3,a2], lo word = [b1,b0,a1,a0] -- one v_perm_b32 each.
__device__ __forceinline__ void make_afrag(const unsigned* u, bf16x8& ah, bf16x8& al){
    FragU hi, lo;
#pragma unroll
    for (int i = 0; i < 4; ++i){
        unsigned a = u[2*i], b = u[2*i+1];
        hi.w[i] = __builtin_amdgcn_perm(b, a, 0x07060302u);
        lo.w[i] = __builtin_amdgcn_perm(b, a, 0x05040100u);
    }
    ah = hi.v; al = lo.v;
}

__device__ __forceinline__ u64 ald64(const u64* p){
    return __hip_atomic_load(p, __ATOMIC_RELAXED, __HIP_MEMORY_SCOPE_AGENT);
}
__device__ __forceinline__ void ast64(u64* p, u64 v){
    __hip_atomic_store(p, v, __ATOMIC_RELAXED, __HIP_MEMORY_SCOPE_AGENT);
}
// 16B speculative read via two relaxed agent loads.
__device__ __forceinline__ i32x4 ald128(const unsigned* p){
    u64 a = ald64((const u64*)p);
    u64 b = ald64((const u64*)p + 1);
    i32x4 v;
    v[0] = (int)(unsigned)a; v[1] = (int)(unsigned)(a >> 32);
    v[2] = (int)(unsigned)b; v[3] = (int)(unsigned)(b >> 32);
    return v;
}

// all 4 words must have bit0 == tag
__device__ __forceinline__ bool bad4(const i32x4& v, unsigned tag){
    unsigned x = ((unsigned)v[0] ^ tag) | ((unsigned)v[1] ^ tag)
               | ((unsigned)v[2] ^ tag) | ((unsigned)v[3] ^ tag);
    return (x & 1u) != 0u;
}
// serial retry: agent loads, SERIALIZED (rate limiter -- R7/R8 lesson).
__device__ __forceinline__ void fix4(const unsigned* p, unsigned tag, i32x4& v){
    if (bad4(v, tag)){
        for (;;){
            u64 a = ald64((const u64*)p);
            u64 b = ald64((const u64*)p + 1);
            v[0] = (int)(unsigned)a; v[1] = (int)(unsigned)(a >> 32);
            v[2] = (int)(unsigned)b; v[3] = (int)(unsigned)(b >> 32);
            if (!bad4(v, tag)) break;
            __builtin_amdgcn_s_sleep(1);
        }
    }
}
// one parallel probe round over all still-bad chunks; returns updated mask.
template<int N>
__device__ __forceinline__ unsigned probeRound(unsigned bad,
                                               const unsigned* const (&p)[N],
                                               const unsigned (&tg)[N],
                                               i32x4 (&v)[N]){
    u64 A[N], B[N];
#pragma unroll
    for (int i = 0; i < N; ++i) if (bad & (1u << i)){
        A[i] = ald64((const u64*)p[i]);
        B[i] = ald64((const u64*)p[i] + 1);
    }
#pragma unroll
    for (int i = 0; i < N; ++i) if (bad & (1u << i)){
        i32x4 nv;
        nv[0] = (int)(unsigned)A[i]; nv[1] = (int)(unsigned)(A[i] >> 32);
        nv[2] = (int)(unsigned)B[i]; nv[3] = (int)(unsigned)(B[i] >> 32);
        v[i] = nv;
        if (!bad4(nv, tg[i])) bad &= ~(1u << i);
    }
    return bad;
}
// serial-first-then-batch: chunk-0 spin absorbs the visibility wait, then
// one parallel re-probe (1 RTT) covers the rest; stragglers go serial.
template<int N>
__device__ __forceinline__ void fixS(const unsigned* const (&p)[N],
                                     const unsigned (&tg)[N], i32x4 (&v)[N]){
    unsigned bad = 0;
#pragma unroll
    for (int i = 0; i < N; ++i) bad |= (unsigned)bad4(v[i], tg[i]) << i;
    if (__builtin_expect(bad == 0u, 1)) return;
    // (1) serial-fix the FIRST stale chunk (rate-limited wait absorber)
    bool done = false;
#pragma unroll
    for (int i = 0; i < N; ++i){
        if (!done && (bad & (1u << i))){
            fix4(p[i], tg[i], v[i]);
            bad &= ~(1u << i);
            done = true;
        }
    }
    if (bad == 0u) return;
    // (2) one parallel re-probe -- data is visible now in the common case
    bad = probeRound<N>(bad, p, tg, v);
    // (3) stragglers: storm-safe serialized path
#pragma unroll
    for (int i = 0; i < N; ++i) if (bad & (1u << i)) fix4(p[i], tg[i], v[i]);
}

template<bool BIG>
__global__ __launch_bounds__(512, 1) void gru_main(
    const float* __restrict__ X,
    const float* __restrict__ Wih0, const float* __restrict__ Whh0,
    const float* __restrict__ bih0, const float* __restrict__ bhh0,
    const float* __restrict__ Wih1, const float* __restrict__ Whh1,
    const float* __restrict__ bih1, const float* __restrict__ bhh1,
    const float* __restrict__ fcW, const float* __restrict__ fcb,
    float* __restrict__ out,
    unsigned* hseq0, unsigned* hseq1)
{
    // Kill stale clean L1/L2 lines left from the previous graph replay.
    __builtin_amdgcn_fence(__ATOMIC_ACQUIRE, "agent");

    __shared__ unsigned Alds[16 * S1];
    __shared__ float P[8][3][16 * PR];
    __shared__ unsigned hout[256];

    const int tid  = threadIdx.x;
    const int lane = tid & 63;
    const int w    = tid >> 6;
    const bool isL1 = blockIdx.x >= 128;
    const int lb = isL1 ? (int)blockIdx.x - 128 : (int)blockIdx.x;
    const int m  = lb >> 5;                // batch tile 0..3
    const int cb = lb & 31;                // col-block 0..31
    const int c0 = cb * 16;
    const int STR  = isL1 ? S1 : S0;
    const int HOFF = isL1 ? 512 : 128;

    const bool active = isL1 || (w < 5);   // layer0 K=640 -> 5 waves x 128

    // ---- register-resident weight fragments (hi/lo split-bf16) ----
    bf16x8 whi[4][3], wlo[4][3];
    if (active){
        const int n = lane & 15;
#pragma unroll
        for (int ks = 0; ks < 4; ++ks){
            int kq = w * 128 + ks * 32 + (lane >> 4) * 8;
            const float* src; long kloc, rowlen;
            if (isL1){
                if (kq < 512){ src = Wih1; kloc = kq; } else { src = Whh1; kloc = kq - 512; }
                rowlen = 512;
            } else {
                if (kq < 128){ src = Wih0; kloc = kq; rowlen = 128; }
                else         { src = Whh0; kloc = kq - 128; rowlen = 512; }
            }
#pragma unroll
            for (int g = 0; g < 3; ++g){
                long row = (long)g * Hh + c0 + n;
                make_wfrag(src + row * rowlen + kloc, whi[ks][g], wlo[ks][g]);
            }
        }
    }
    // ---- biases for epilogue ----
    float Br = 0.f, Bz = 0.f, Bin = 0.f, Bhn = 0.f;
    if (tid < 256){
        int c = c0 + (tid & 15);
        const float* bi = isL1 ? bih1 : bih0;
        const float* bh = isL1 ? bhh1 : bhh0;
        Br  = bi[c] + bh[c];
        Bz  = bi[Hh + c] + bh[Hh + c];
        Bin = bi[2*Hh + c];
        Bhn = bh[2*Hh + c];
    }

    for (int t = 0; t < Tt; ++t){
        // ---- staging: agent-first speculative loads + fixS fix-up ----
        if (isL1){
            const unsigned* s0 = hseq0 + ((long)t * Bb + m*16) * (long)Hh;
            long r1 = BIG ? (long)(t-1) * BH : (long)((t-1) & 1) * BH;
            const unsigned* s1 = hseq1 + r1 + (long)(m*16) * Hh;
            unsigned tag1 = BIG ? 1u : (1u - (((unsigned)(t-1) >> 1) & 1u));
            if (t > 0){
                const unsigned* aP[8]; unsigned tg[8]; i32x4 vv[8];
#pragma unroll
                for (int it = 0; it < 4; ++it){
                    int j = it*512 + tid; int row = j >> 7, col = (j & 127) * 4;
                    aP[it] = s0 + (long)row * Hh + col;
                    vv[it] = ald128(aP[it]);
                    tg[it] = 1u;
                }
#pragma unroll
                for (int it = 0; it < 4; ++it){
                    int j = it*512 + tid; int row = j >> 7, col = (j & 127) * 4;
                    aP[4+it] = s1 + (long)row * Hh + col;
                    vv[4+it] = ald128(aP[4+it]);
                    tg[4+it] = tag1;
                }
                fixS<8>(aP, tg, vv);
#pragma unroll
                for (int it = 0; it < 4; ++it){
                    int j = it*512 + tid; int row = j >> 7, col = (j & 127) * 4;
                    *(i32x4*)(Alds + row * S1 + col) = vv[it];
                    *(i32x4*)(Alds + row * S1 + 512 + col) = vv[4+it];
                }
            } else {
                const unsigned* aP[4]; unsigned tg[4]; i32x4 vv[4];
#pragma unroll
                for (int it = 0; it < 4; ++it){
                    int j = it*512 + tid; int row = j >> 7, col = (j & 127) * 4;
                    aP[it] = s0 + (long)row * Hh + col;
                    vv[it] = ald128(aP[it]);
                    tg[it] = 1u;
                }
                fixS<4>(aP, tg, vv);
#pragma unroll
                for (int it = 0; it < 4; ++it){
                    int j = it*512 + tid; int row = j >> 7, col = (j & 127) * 4;
                    *(i32x4*)(Alds + row * S1 + col) = vv[it];
                    *(i32x4*)(Alds + row * S1 + 512 + col) = i32x4{0,0,0,0};
                }
            }
        } else {
            // issue speculative h loads FIRST, pack X while they fly
            const unsigned* aP[4]; unsigned tg[4]; i32x4 vv[4];
            if (t > 0){
                const unsigned* s0 = hseq0 + ((long)(t-1) * Bb + m*16) * (long)Hh;
#pragma unroll
                for (int it = 0; it < 4; ++it){
                    int j = it*512 + tid; int row = j >> 7, col = (j & 127) * 4;
                    aP[it] = s0 + (long)row * Hh + col;
                    vv[it] = ald128(aP[it]);
                    tg[it] = 1u;
                }
            }
            // X[t] fp32 (cached input) -> pack on the fly
            {
                int row = tid >> 5, c4 = (tid & 31) * 4;
                f32x4 xv = *(const f32x4*)(X + ((long)(m*16 + row) * Tt + t) * DIN + c4);
                i32x4 pv;
                pv[0] = (int)pack_split(xv[0]);
                pv[1] = (int)pack_split(xv[1]);
                pv[2] = (int)pack_split(xv[2]);
                pv[3] = (int)pack_split(xv[3]);
                *(i32x4*)(Alds + row * S0 + c4) = pv;
            }
            if (t > 0){
                fixS<4>(aP, tg, vv);
#pragma unroll
                for (int it = 0; it < 4; ++it){
                    int j = it*512 + tid; int row = j >> 7, col = (j & 127) * 4;
                    *(i32x4*)(Alds + row * S0 + 128 + col) = vv[it];
                }
            } else {
#pragma unroll
                for (int it = 0; it < 8; ++it){
                    int j = it*512 + tid;
                    *(u64*)(Alds + (j >> 8) * S0 + 128 + (j & 255) * 2) = 0ULL;
                }
            }
        }
        __syncthreads();

        // ---- MFMA: this wave's K-slice, tiles {r, z, nx-or-nh} ----
        if (active){
            f32x4 a0 = {0.f,0.f,0.f,0.f}, a1 = a0, a2 = a0;
            const unsigned* arow = Alds + (lane & 15) * STR + w * 128 + (lane >> 4) * 8;
#pragma unroll
            for (int ks = 0; ks < 4; ++ks){
                unsigned uu[8];
                *(i32x4*)&uu[0] = *(const i32x4*)(arow + ks*32);
                *(i32x4*)&uu[4] = *(const i32x4*)(arow + ks*32 + 4);
                bf16x8 ah, al; make_afrag(uu, ah, al);
                a0 = MFMA16(ah, whi[ks][0], a0, 0,0,0);
                a0 = MFMA16(ah, wlo[ks][0], a0, 0,0,0);
                a0 = MFMA16(al, whi[ks][0], a0, 0,0,0);
                a1 = MFMA16(ah, whi[ks][1], a1, 0,0,0);
                a1 = MFMA16(ah, wlo[ks][1], a1, 0,0,0);
                a1 = MFMA16(al, whi[ks][1], a1, 0,0,0);
                a2 = MFMA16(ah, whi[ks][2], a2, 0,0,0);
                a2 = MFMA16(ah, wlo[ks][2], a2, 0,0,0);
                a2 = MFMA16(al, whi[ks][2], a2, 0,0,0);
            }
            int q = lane >> 4, n = lane & 15;
#pragma unroll
            for (int r4 = 0; r4 < 4; ++r4){
                int idx = (q*4 + r4)*PR + n;
                P[w][0][idx] = a0[r4];
                P[w][1][idx] = a1[r4];
                P[w][2][idx] = a2[r4];
            }
        }
        __syncthreads();

        // ---- reduce partials + gates -> tagged packed h into LDS ----
        unsigned wtag = isL1 ? (BIG ? 1u : (1u - (((unsigned)t >> 1) & 1u))) : 1u;
        if (tid < 256){
            int bm = tid >> 4, n = tid & 15;
            int idx = bm * PR + n;
            float sr, sz, snx, snh;
            if (isL1){
                sr  = P[0][0][idx]+P[1][0][idx]+P[2][0][idx]+P[3][0][idx]
                    + P[4][0][idx]+P[5][0][idx]+P[6][0][idx]+P[7][0][idx];
                sz  = P[0][1][idx]+P[1][1][idx]+P[2][1][idx]+P[3][1][idx]
                    + P[4][1][idx]+P[5][1][idx]+P[6][1][idx]+P[7][1][idx];
                snx = P[0][2][idx]+P[1][2][idx]+P[2][2][idx]+P[3][2][idx];
                snh = P[4][2][idx]+P[5][2][idx]+P[6][2][idx]+P[7][2][idx];
            } else {
                sr  = P[0][0][idx]+P[1][0][idx]+P[2][0][idx]+P[3][0][idx]+P[4][0][idx];
                sz  = P[0][1][idx]+P[1][1][idx]+P[2][1][idx]+P[3][1][idx]+P[4][1][idx];
                snx = P[0][2][idx];
                snh = P[1][2][idx]+P[2][2][idx]+P[3][2][idx]+P[4][2][idx];
            }
            float r  = 1.f/(1.f + __expf(-(sr + Br)));
            float z  = 1.f/(1.f + __expf(-(sz + Bz)));
            float ee = __expf(2.f*(snx + Bin + r*(snh + Bhn)));
            float nn = 1.f - 2.f/(ee + 1.f);
            float hp = unpack_f32(Alds[bm*STR + HOFF + c0 + n]);
            float hnew = (1.f - z)*nn + z*hp;
            hout[tid] = (pack_split(hnew) & ~1u) | wtag;   // hout[bm*16 + n]
        }
        __syncthreads();

        // ---- agent u64 stores; NO ack wait, NO flag — sail into t+1 ----
        if (tid < 128){
            int bm = tid >> 3, k = (tid & 7) * 2;
            u64 v = (u64)hout[bm*16 + k] | ((u64)hout[bm*16 + k + 1] << 32);
            unsigned* base = isL1
                ? hseq1 + (BIG ? (long)t * BH : (long)(t & 1) * BH)
                : hseq0 + (long)t * BH;
            ast64((u64*)(base + (long)(m*16 + bm) * Hh + c0 + k), v);
        }
    }

    // ---- FC epilogue: one layer1 block per m, validated reads ----
    if (isL1 && cb == 31){
        unsigned ftag = BIG ? 1u : (1u - (((unsigned)(Tt-1) >> 1) & 1u));
        const unsigned* hb = hseq1 + (BIG ? (long)(Tt-1) * BH : (long)((Tt-1) & 1) * BH);
        int half = lane >> 5, l5 = lane & 31;
        int b = m*16 + w*2 + half;
        const u64* hrow = (const u64*)(hb + (long)b * Hh);
        float p = 0.f;
#pragma unroll
        for (int i = 0; i < 8; ++i){
            int k = l5 + 32*i;
            u64 v = ald64(hrow + k);
            while (((((unsigned)v ^ ftag) | ((unsigned)(v >> 32) ^ ftag)) & 1u) != 0u){
                __builtin_amdgcn_s_sleep(1);
                v = ald64(hrow + k);
            }
            p += unpack_f32((unsigned)v) * fcW[2*k]
               + unpack_f32((unsigned)(v >> 32)) * fcW[2*k+1];
        }
#pragma unroll
        for (int off = 16; off > 0; off >>= 1) p += __shfl_xor(p, off);
        if (l5 == 0) out[b] = p + fcb[0];
    }
}

extern "C" void kernel_launch(void* const* d_in, const int* in_sizes, int n_in,
                              void* d_out, int out_size, void* d_ws, size_t ws_size,
                              hipStream_t stream) {
    const float* X    = (const float*)d_in[0];
    const float* Wih0 = (const float*)d_in[1];
    const float* Whh0 = (const float*)d_in[2];
    const float* bih0 = (const float*)d_in[3];
    const float* bhh0 = (const float*)d_in[4];
    const float* Wih1 = (const float*)d_in[5];
    const float* Whh1 = (const float*)d_in[6];
    const float* bih1 = (const float*)d_in[7];
    const float* bhh1 = (const float*)d_in[8];
    const float* fcW  = (const float*)d_in[9];
    const float* fcb  = (const float*)d_in[10];
    float* out = (float*)d_out;

    // ws: hseq0 64 MiB | hseq1 64 MiB (BIG) or 256 KiB ring. No flags, no memset:
    // harness poisons ws to 0xAA (bit0=0 = invalid) before every launch.
    unsigned* hseq0 = (unsigned*)d_ws;
    unsigned* hseq1 = hseq0 + (long)Tt * BH;
    size_t need_big = (size_t)2 * Tt * BH * 4;    // 128 MiB
    bool big = ws_size >= need_big;

    if (big)
        gru_main<true><<<256, 512, 0, stream>>>(X, Wih0, Whh0, bih0, bhh0,
                                                Wih1, Whh1, bih1, bhh1, fcW, fcb,
                                                out, hseq0, hseq1);
    else
        gru_main<false><<<256, 512, 0, stream>>>(X, Wih0, Whh0, bih0, bhh0,
                                                 Wih1, Whh1, bih1, bhh1, fcW, fcb,
                                                 out, hseq0, hseq1);
}

// Round 17
// 1693.784 us; speedup vs baseline: 1.5354x; 1.5354x over previous
//
#include <hip/hip_runtime.h>

// GRU B=64, T=512, IN=128, H=512, L=2, OUT=1 (fp32 in/out).
// R15: R12 base + 16-byte agent-scope memory ops (same bytes, HALF the
// transaction count on the MALL coherence path).
//   Post-mortem R13b/R14: ALL parallel-retry schedules regress vs R12's
//   serialized chain -- per-chunk validity is paced by producer store
//   DRAIN, which the serial chain already matches. R12's ~6500cyc/step
//   exchange wait is too big for any latency chain => the agent-op path
//   is TRANSACTION-RATE bound (each 8B agent op = a directory event;
//   WRITE runs at only 77 GB/s effective). Every round since R6 used 8B
//   agent ops. Changes (surgical, all else byte-identical to R12):
//   - fix4 retry: one global_load_dwordx4 sc1 (16B device-scope) replaces
//     2x ald64 (sc-flags on global ops HW-verified by R10's sc0 probe).
//   - gate stores: 64x global_store_dwordx4 sc1 replaces 128x u64 atomics.
//   Initial speculative loads stay compiler-batched 2xald64 (no per-op
//   vmcnt(0) serialization). hout, 3 barriers, serial fix4: unchanged.
// History: R9=1723 R10(remap)=2906 R11(reg-direct)=1935 R12(agent-spec)=1702
//          R13b(batch-first)=2561 R14(serial-then-batch)=2601.

constexpr int Bb = 64, Tt = 512, DIN = 128, Hh = 512;
constexpr int BH = Bb * Hh;
constexpr int S0 = 644;    // LDS A-row stride (u32), layer0: 128 x + 512 h + 4 pad
constexpr int S1 = 1028;   // layer1: 512 h0 + 512 h1 + 4 pad
constexpr int PR = 20;     // partials row stride: conflict-free (2-way) writes

typedef float  f32x4  __attribute__((ext_vector_type(4)));
typedef short  bf16x8 __attribute__((ext_vector_type(8)));
typedef int    i32x4  __attribute__((ext_vector_type(4)));
typedef unsigned long long u64;

#define MFMA16 __builtin_amdgcn_mfma_f32_16x16x32_bf16

__device__ __forceinline__ unsigned rne_bf16(unsigned xb){
    return (xb + 0x7FFFu + ((xb >> 16) & 1u)) >> 16;
}
__device__ __forceinline__ unsigned pack_split(float x){
    unsigned hb = rne_bf16(__float_as_uint(x));
    float hf = __uint_as_float(hb << 16);
    unsigned lb = rne_bf16(__float_as_uint(x - hf));
    return (hb << 16) | lb;
}
__device__ __forceinline__ float unpack_f32(unsigned u){
    return __uint_as_float(u & 0xFFFF0000u) + __uint_as_float(u << 16);
}

union FragU { unsigned w[4]; bf16x8 v; };

__device__ __forceinline__ void make_wfrag(const float* p, bf16x8& wh, bf16x8& wl){
    FragU hi, lo;
#pragma unroll
    for (int i = 0; i < 4; ++i){
        unsigned pa = pack_split(p[2*i]), pb = pack_split(p[2*i+1]);
        hi.w[i] = (pa >> 16) | (pb & 0xFFFF0000u);
        lo.w[i] = (pa & 0xFFFFu) | (pb << 16);
    }
    wh = hi.v; wl = lo.v;
}
// hi word = [b3,b2,a3,a2], lo word = [b1,b0,a1,a0] -- one v_perm_b32 each.
__device__ __forceinline__ void make_afrag(const unsigned* u, bf16x8& ah, bf16x8& al){
    FragU hi, lo;
#pragma unroll
    for (int i = 0; i < 4; ++i){
        unsigned a = u[2*i], b = u[2*i+1];
        hi.w[i] = __builtin_amdgcn_perm(b, a, 0x07060302u);
        lo.w[i] = __builtin_amdgcn_perm(b, a, 0x05040100u);
    }
    ah = hi.v; al = lo.v;
}

__device__ __forceinline__ u64 ald64(const u64* p){
    return __hip_atomic_load(p, __ATOMIC_RELAXED, __HIP_MEMORY_SCOPE_AGENT);
}
// 16B speculative read via two relaxed agent loads (compiler batches the
// waitcnt across the whole initial probe batch -- keep for issue phase).
__device__ __forceinline__ i32x4 ald128(const unsigned* p){
    u64 a = ald64((const u64*)p);
    u64 b = ald64((const u64*)p + 1);
    i32x4 v;
    v[0] = (int)(unsigned)a; v[1] = (int)(unsigned)(a >> 32);
    v[2] = (int)(unsigned)b; v[3] = (int)(unsigned)(b >> 32);
    return v;
}
// 16B device-scope load in ONE transaction (sc1 = device scope, bypasses
// stale-capable L1/L2 copies; R10 verified sc-flags assemble on global ops).
// Internal vmcnt(0): used only in the already-serialized retry loop.
__device__ __forceinline__ i32x4 ald128a(const unsigned* p){
    i32x4 r;
    asm volatile("global_load_dwordx4 %0, %1, off sc1\n\t"
                 "s_waitcnt vmcnt(0)"
                 : "=v"(r) : "v"(p) : "memory");
    return r;
}
// 16B device-scope store in ONE transaction (tags in every word keep
// per-word visibility safe regardless of write atomicity).
__device__ __forceinline__ void ast128(unsigned* p, i32x4 v){
    asm volatile("global_store_dwordx4 %0, %1, off sc1"
                 :: "v"(p), "v"(v) : "memory");
}

// all 4 words must have bit0 == tag
__device__ __forceinline__ bool bad4(const i32x4& v, unsigned tag){
    unsigned x = ((unsigned)v[0] ^ tag) | ((unsigned)v[1] ^ tag)
               | ((unsigned)v[2] ^ tag) | ((unsigned)v[3] ^ tag);
    return (x & 1u) != 0u;
}
// serial retry: SERIALIZED per chunk (rate limiter -- R7/R8/R13b/R14
// lesson: every parallel-retry variant regresses). 16B single-transaction
// probe halves the retry's MALL transaction load vs 2x ald64.
__device__ __forceinline__ void fix4(const unsigned* p, unsigned tag, i32x4& v){
    if (bad4(v, tag)){
        for (;;){
            v = ald128a(p);
            if (!bad4(v, tag)) break;
            __builtin_amdgcn_s_sleep(1);
        }
    }
}

template<bool BIG>
__global__ __launch_bounds__(512, 1) void gru_main(
    const float* __restrict__ X,
    const float* __restrict__ Wih0, const float* __restrict__ Whh0,
    const float* __restrict__ bih0, const float* __restrict__ bhh0,
    const float* __restrict__ Wih1, const float* __restrict__ Whh1,
    const float* __restrict__ bih1, const float* __restrict__ bhh1,
    const float* __restrict__ fcW, const float* __restrict__ fcb,
    float* __restrict__ out,
    unsigned* hseq0, unsigned* hseq1)
{
    // Kill stale clean L1/L2 lines left from the previous graph replay.
    __builtin_amdgcn_fence(__ATOMIC_ACQUIRE, "agent");

    __shared__ unsigned Alds[16 * S1];
    __shared__ float P[8][3][16 * PR];
    __shared__ unsigned hout[256];

    const int tid  = threadIdx.x;
    const int lane = tid & 63;
    const int w    = tid >> 6;
    const bool isL1 = blockIdx.x >= 128;
    const int lb = isL1 ? (int)blockIdx.x - 128 : (int)blockIdx.x;
    const int m  = lb >> 5;                // batch tile 0..3
    const int cb = lb & 31;                // col-block 0..31
    const int c0 = cb * 16;
    const int STR  = isL1 ? S1 : S0;
    const int HOFF = isL1 ? 512 : 128;

    const bool active = isL1 || (w < 5);   // layer0 K=640 -> 5 waves x 128

    // ---- register-resident weight fragments (hi/lo split-bf16) ----
    bf16x8 whi[4][3], wlo[4][3];
    if (active){
        const int n = lane & 15;
#pragma unroll
        for (int ks = 0; ks < 4; ++ks){
            int kq = w * 128 + ks * 32 + (lane >> 4) * 8;
            const float* src; long kloc, rowlen;
            if (isL1){
                if (kq < 512){ src = Wih1; kloc = kq; } else { src = Whh1; kloc = kq - 512; }
                rowlen = 512;
            } else {
                if (kq < 128){ src = Wih0; kloc = kq; rowlen = 128; }
                else         { src = Whh0; kloc = kq - 128; rowlen = 512; }
            }
#pragma unroll
            for (int g = 0; g < 3; ++g){
                long row = (long)g * Hh + c0 + n;
                make_wfrag(src + row * rowlen + kloc, whi[ks][g], wlo[ks][g]);
            }
        }
    }
    // ---- biases for epilogue ----
    float Br = 0.f, Bz = 0.f, Bin = 0.f, Bhn = 0.f;
    if (tid < 256){
        int c = c0 + (tid & 15);
        const float* bi = isL1 ? bih1 : bih0;
        const float* bh = isL1 ? bhh1 : bhh0;
        Br  = bi[c] + bh[c];
        Bz  = bi[Hh + c] + bh[Hh + c];
        Bin = bi[2*Hh + c];
        Bhn = bh[2*Hh + c];
    }

    for (int t = 0; t < Tt; ++t){
        // ---- staging: agent-first speculative loads + serialized fix-up ----
        if (isL1){
            const unsigned* s0 = hseq0 + ((long)t * Bb + m*16) * (long)Hh;
            long r1 = BIG ? (long)(t-1) * BH : (long)((t-1) & 1) * BH;
            const unsigned* s1 = hseq1 + r1 + (long)(m*16) * Hh;
            unsigned tag1 = BIG ? 1u : (1u - (((unsigned)(t-1) >> 1) & 1u));
            const unsigned* a0[4]; const unsigned* a1[4];
            i32x4 v0[4], v1[4];
#pragma unroll
            for (int it = 0; it < 4; ++it){
                int j = it*512 + tid; int row = j >> 7, col = (j & 127) * 4;
                a0[it] = s0 + (long)row * Hh + col;
                v0[it] = ald128(a0[it]);
            }
            if (t > 0){
#pragma unroll
                for (int it = 0; it < 4; ++it){
                    int j = it*512 + tid; int row = j >> 7, col = (j & 127) * 4;
                    a1[it] = s1 + (long)row * Hh + col;
                    v1[it] = ald128(a1[it]);
                }
            }
#pragma unroll
            for (int it = 0; it < 4; ++it) fix4(a0[it], 1u, v0[it]);
            if (t > 0){
#pragma unroll
                for (int it = 0; it < 4; ++it) fix4(a1[it], tag1, v1[it]);
            } else {
#pragma unroll
                for (int it = 0; it < 4; ++it) v1[it] = i32x4{0,0,0,0};
            }
#pragma unroll
            for (int it = 0; it < 4; ++it){
                int j = it*512 + tid; int row = j >> 7, col = (j & 127) * 4;
                *(i32x4*)(Alds + row * S1 + col) = v0[it];
                *(i32x4*)(Alds + row * S1 + 512 + col) = v1[it];
            }
        } else {
            // X[t] fp32 (cached input) -> pack on the fly
            {
                int row = tid >> 5, c4 = (tid & 31) * 4;
                f32x4 xv = *(const f32x4*)(X + ((long)(m*16 + row) * Tt + t) * DIN + c4);
                i32x4 pv;
                pv[0] = (int)pack_split(xv[0]);
                pv[1] = (int)pack_split(xv[1]);
                pv[2] = (int)pack_split(xv[2]);
                pv[3] = (int)pack_split(xv[3]);
                *(i32x4*)(Alds + row * S0 + c4) = pv;
            }
            if (t > 0){
                const unsigned* s0 = hseq0 + ((long)(t-1) * Bb + m*16) * (long)Hh;
                const unsigned* a0[4]; i32x4 v0[4];
#pragma unroll
                for (int it = 0; it < 4; ++it){
                    int j = it*512 + tid; int row = j >> 7, col = (j & 127) * 4;
                    a0[it] = s0 + (long)row * Hh + col;
                    v0[it] = ald128(a0[it]);
                }
#pragma unroll
                for (int it = 0; it < 4; ++it) fix4(a0[it], 1u, v0[it]);
#pragma unroll
                for (int it = 0; it < 4; ++it){
                    int j = it*512 + tid; int row = j >> 7, col = (j & 127) * 4;
                    *(i32x4*)(Alds + row * S0 + 128 + col) = v0[it];
                }
            } else {
#pragma unroll
                for (int it = 0; it < 8; ++it){
                    int j = it*512 + tid;
                    *(u64*)(Alds + (j >> 8) * S0 + 128 + (j & 255) * 2) = 0ULL;
                }
            }
        }
        __syncthreads();

        // ---- MFMA: this wave's K-slice, tiles {r, z, nx-or-nh} ----
        if (active){
            f32x4 a0 = {0.f,0.f,0.f,0.f}, a1 = a0, a2 = a0;
            const unsigned* arow = Alds + (lane & 15) * STR + w * 128 + (lane >> 4) * 8;
#pragma unroll
            for (int ks = 0; ks < 4; ++ks){
                unsigned uu[8];
                *(i32x4*)&uu[0] = *(const i32x4*)(arow + ks*32);
                *(i32x4*)&uu[4] = *(const i32x4*)(arow + ks*32 + 4);
                bf16x8 ah, al; make_afrag(uu, ah, al);
                a0 = MFMA16(ah, whi[ks][0], a0, 0,0,0);
                a0 = MFMA16(ah, wlo[ks][0], a0, 0,0,0);
                a0 = MFMA16(al, whi[ks][0], a0, 0,0,0);
                a1 = MFMA16(ah, whi[ks][1], a1, 0,0,0);
                a1 = MFMA16(ah, wlo[ks][1], a1, 0,0,0);
                a1 = MFMA16(al, whi[ks][1], a1, 0,0,0);
                a2 = MFMA16(ah, whi[ks][2], a2, 0,0,0);
                a2 = MFMA16(ah, wlo[ks][2], a2, 0,0,0);
                a2 = MFMA16(al, whi[ks][2], a2, 0,0,0);
            }
            int q = lane >> 4, n = lane & 15;
#pragma unroll
            for (int r4 = 0; r4 < 4; ++r4){
                int idx = (q*4 + r4)*PR + n;
                P[w][0][idx] = a0[r4];
                P[w][1][idx] = a1[r4];
                P[w][2][idx] = a2[r4];
            }
        }
        __syncthreads();

        // ---- reduce partials + gates -> tagged packed h into LDS ----
        unsigned wtag = isL1 ? (BIG ? 1u : (1u - (((unsigned)t >> 1) & 1u))) : 1u;
        if (tid < 256){
            int bm = tid >> 4, n = tid & 15;
            int idx = bm * PR + n;
            float sr, sz, snx, snh;
            if (isL1){
                sr  = P[0][0][idx]+P[1][0][idx]+P[2][0][idx]+P[3][0][idx]
                    + P[4][0][idx]+P[5][0][idx]+P[6][0][idx]+P[7][0][idx];
                sz  = P[0][1][idx]+P[1][1][idx]+P[2][1][idx]+P[3][1][idx]
                    + P[4][1][idx]+P[5][1][idx]+P[6][1][idx]+P[7][1][idx];
                snx = P[0][2][idx]+P[1][2][idx]+P[2][2][idx]+P[3][2][idx];
                snh = P[4][2][idx]+P[5][2][idx]+P[6][2][idx]+P[7][2][idx];
            } else {
                sr  = P[0][0][idx]+P[1][0][idx]+P[2][0][idx]+P[3][0][idx]+P[4][0][idx];
                sz  = P[0][1][idx]+P[1][1][idx]+P[2][1][idx]+P[3][1][idx]+P[4][1][idx];
                snx = P[0][2][idx];
                snh = P[1][2][idx]+P[2][2][idx]+P[3][2][idx]+P[4][2][idx];
            }
            float r  = 1.f/(1.f + __expf(-(sr + Br)));
            float z  = 1.f/(1.f + __expf(-(sz + Bz)));
            float ee = __expf(2.f*(snx + Bin + r*(snh + Bhn)));
            float nn = 1.f - 2.f/(ee + 1.f);
            float hp = unpack_f32(Alds[bm*STR + HOFF + c0 + n]);
            float hnew = (1.f - z)*nn + z*hp;
            hout[tid] = (pack_split(hnew) & ~1u) | wtag;   // hout[bm*16 + n]
        }
        __syncthreads();

        // ---- 16B device-scope stores; NO ack wait, NO flag ----
        if (tid < 64){
            int bm = tid >> 2, k = (tid & 3) * 4;
            i32x4 v;
            v[0] = (int)hout[bm*16 + k];
            v[1] = (int)hout[bm*16 + k + 1];
            v[2] = (int)hout[bm*16 + k + 2];
            v[3] = (int)hout[bm*16 + k + 3];
            unsigned* base = isL1
                ? hseq1 + (BIG ? (long)t * BH : (long)(t & 1) * BH)
                : hseq0 + (long)t * BH;
            ast128(base + (long)(m*16 + bm) * Hh + c0 + k, v);
        }
    }

    // ---- FC epilogue: one layer1 block per m, validated reads ----
    if (isL1 && cb == 31){
        unsigned ftag = BIG ? 1u : (1u - (((unsigned)(Tt-1) >> 1) & 1u));
        const unsigned* hb = hseq1 + (BIG ? (long)(Tt-1) * BH : (long)((Tt-1) & 1) * BH);
        int half = lane >> 5, l5 = lane & 31;
        int b = m*16 + w*2 + half;
        const u64* hrow = (const u64*)(hb + (long)b * Hh);
        float p = 0.f;
#pragma unroll
        for (int i = 0; i < 8; ++i){
            int k = l5 + 32*i;
            u64 v = ald64(hrow + k);
            while (((((unsigned)v ^ ftag) | ((unsigned)(v >> 32) ^ ftag)) & 1u) != 0u){
                __builtin_amdgcn_s_sleep(1);
                v = ald64(hrow + k);
            }
            p += unpack_f32((unsigned)v) * fcW[2*k]
               + unpack_f32((unsigned)(v >> 32)) * fcW[2*k+1];
        }
#pragma unroll
        for (int off = 16; off > 0; off >>= 1) p += __shfl_xor(p, off);
        if (l5 == 0) out[b] = p + fcb[0];
    }
}

extern "C" void kernel_launch(void* const* d_in, const int* in_sizes, int n_in,
                              void* d_out, int out_size, void* d_ws, size_t ws_size,
                              hipStream_t stream) {
    const float* X    = (const float*)d_in[0];
    const float* Wih0 = (const float*)d_in[1];
    const float* Whh0 = (const float*)d_in[2];
    const float* bih0 = (const float*)d_in[3];
    const float* bhh0 = (const float*)d_in[4];
    const float* Wih1 = (const float*)d_in[5];
    const float* Whh1 = (const float*)d_in[6];
    const float* bih1 = (const float*)d_in[7];
    const float* bhh1 = (const float*)d_in[8];
    const float* fcW  = (const float*)d_in[9];
    const float* fcb  = (const float*)d_in[10];
    float* out = (float*)d_out;

    // ws: hseq0 64 MiB | hseq1 64 MiB (BIG) or 256 KiB ring. No flags, no memset:
    // harness poisons ws to 0xAA (bit0=0 = invalid) before every launch.
    unsigned* hseq0 = (unsigned*)d_ws;
    unsigned* hseq1 = hseq0 + (long)Tt * BH;
    size_t need_big = (size_t)2 * Tt * BH * 4;    // 128 MiB
    bool big = ws_size >= need_big;

    if (big)
        gru_main<true><<<256, 512, 0, stream>>>(X, Wih0, Whh0, bih0, bhh0,
                                                Wih1, Whh1, bih1, bhh1, fcW, fcb,
                                                out, hseq0, hseq1);
    else
        gru_main<false><<<256, 512, 0, stream>>>(X, Wih0, Whh0, bih0, bhh0,
                                                 Wih1, Whh1, bih1, bhh1, fcW, fcb,
                                                 out, hseq0, hseq1);
}